// Round 13
// baseline (311.520 us; speedup 1.0000x reference)
//
#include <hip/hip_runtime.h>
#include <hip/hip_bf16.h>

#define N_VOX 200000
#define CI 128
#define CO 128
#define KK 27
#define BM 192
#define NBLK192 1042
#define NBLKFB 1563
#define NSTEP 54
#define LEAK 0.333f
#define BN_EPS 1e-4f
#define SENT 0x3FFFFu
#define ACC_STRIDE 132   // u16 units
#define RB_CAP 64

typedef unsigned short u16;
typedef unsigned int u32;
typedef __attribute__((ext_vector_type(8))) short short8;
typedef __attribute__((ext_vector_type(4))) float f32x4;

typedef const __attribute__((address_space(1))) u32* gptr_t;
typedef __attribute__((address_space(3))) u32* lptr_t;

__device__ __forceinline__ u16 f2bf(float f) {  // RNE
  union { float f; u32 u; } x; x.f = f;
  return (u16)((x.u + 0x7FFFu + ((x.u >> 16) & 1u)) >> 16);
}
__device__ __forceinline__ float bf2f(u16 h) {
  union { u32 u; float f; } x; x.u = ((u32)h) << 16;
  return x.f;
}
__device__ __forceinline__ u16 cvt_bf(float f) {
  union { __hip_bfloat16 h; u16 u; } c;
  c.h = __float2bfloat16(f);
  return c.u;
}
__device__ __forceinline__ int kbase_of(int k) {
  // center (k=13) has BM entries, others RB_CAP
  return (k < 13) ? k * RB_CAP : (k == 13 ? 13 * RB_CAP : 13 * RB_CAP + BM + (k - 14) * RB_CAP);
}

// ---- feature cast f32 -> bf16 ----
__global__ __launch_bounds__(256) void fcast_kernel(const float* __restrict__ f,
                                                    u16* __restrict__ fb) {
  size_t i = ((size_t)blockIdx.x * 256 + threadIdx.x) * 8;
  float4 a = *(const float4*)(f + i);
  float4 b = *(const float4*)(f + i + 4);
  u16 t[8];
  t[0] = cvt_bf(a.x); t[1] = cvt_bf(a.y); t[2] = cvt_bf(a.z); t[3] = cvt_bf(a.w);
  t[4] = cvt_bf(b.x); t[5] = cvt_bf(b.y); t[6] = cvt_bf(b.z); t[7] = cvt_bf(b.w);
  *(uint4*)(fb + i) = *(const uint4*)t;
}

// ---- W repack: chunk = k*32 + nf*4 + ks ; lane (lr,lg):
// Wt3[chunk*512 + lane*8 + e] = bf16(W[k][ks*32+lg*8+e][nf*16+lr]) ----
__global__ __launch_bounds__(256) void wcast3_kernel(const float* __restrict__ W,
                                                     u16* __restrict__ Wt3) {
  int gid = blockIdx.x * 256 + threadIdx.x;  // 55296 total
  int lane = gid & 63, chunk = gid >> 6;
  int ks = chunk & 3, nf = (chunk >> 2) & 7, k = chunk >> 5;
  int lr = lane & 15, lg = lane >> 4;
  int co = nf * 16 + lr;
  int ci0 = ks * 32 + lg * 8;
  const float* Wk = W + (size_t)k * CI * CO;
  u16 t[8];
#pragma unroll
  for (int e = 0; e < 8; ++e) t[e] = f2bf(Wk[(ci0 + e) * CO + co]);
  *(uint4*)(Wt3 + (size_t)gid * 8) = *(const uint4*)t;
}

// ---- sparse conv v8: BM=192, k-major loop w/ B-in-regs reuse, bf16 LDS acc,
//      barrier-free col-partitioned waves, paired tiles w/ interleaved MFMA ----
__global__ __launch_bounds__(256, 2) void conv_sp_kernel(
    const u16* __restrict__ featb, const u16* __restrict__ Wt3,
    const int* __restrict__ nb, const u16* __restrict__ zp,
    float* __restrict__ out, float* __restrict__ partial) {
  __shared__ __align__(16) char smem[58240];
  u16* const accb = (u16*)smem;                  // 50688B [192][132] bf16
  u32* const rb_lds = (u32*)(smem + 50688);      // 7424B (1856 entries)
  int* const cnt_lds = (int*)(smem + 58112);     // 112B
  int* const wcnt = (int*)(smem + 58224);        // 16B
  float* const ps = (float*)smem;                // epilogue alias (8KB)

  const int tid = threadIdx.x;
  const int bid = blockIdx.x;
  const int row0 = bid * BM;
  const int lane = tid & 63;
  const int w = tid >> 6;

  // zero bf16 acc tile
  for (int i = tid; i < (BM * ACC_STRIDE) / 2; i += 256) ((u32*)accb)[i] = 0u;

  // ---- rulebook: per-k compacted (dst<<18|src), 16-padded with SENT ----
  {
    const bool inrow = (tid < BM) && (row0 + tid < N_VOX);
    const int* nbp = nb + (size_t)(row0 + tid) * KK;
    int vv[KK];
#pragma unroll
    for (int k = 0; k < KK; ++k) vv[k] = (k != 13 && inrow) ? nbp[k] : -1;
    if (tid < BM)
      rb_lds[13 * RB_CAP + tid] = ((u32)tid << 18) | (inrow ? (u32)(row0 + tid) : SENT);
    if (tid == 0) cnt_lds[13] = BM;
#pragma unroll
    for (int k = 0; k < KK; ++k) {
      if (k == 13) continue;
      bool valid = vv[k] >= 0;
      unsigned long long m = __ballot(valid);
      if (lane == 0) wcnt[w] = (int)__popcll(m);
      __syncthreads();
      int pos = (int)__popcll(m & ((1ull << lane) - 1ull));
      if (w >= 1) pos += wcnt[0];
      if (w >= 2) pos += wcnt[1];
      if (w >= 3) pos += wcnt[2];
      int cnt = wcnt[0] + wcnt[1] + wcnt[2] + wcnt[3];
      if (cnt > RB_CAP) cnt = RB_CAP;
      int kb = kbase_of(k);
      if (valid && pos < RB_CAP) rb_lds[kb + pos] = ((u32)tid << 18) | (u32)vv[k];
      int pe = (cnt + 15) & ~15;
      for (int i = cnt + tid; i < pe; i += 256) rb_lds[kb + i] = SENT;
      if (tid == 0) cnt_lds[k] = cnt;
      __syncthreads();
    }
  }

  const int wv = w;
  const int lr = lane & 15, lg = lane >> 4;
  const int colbase = wv * 32 + lr;

  auto loadTile = [&](int off, uint4& sc, short8* a) {
    u32 es = rb_lds[off + lr];
    sc = *(const uint4*)&rb_lds[off + lg * 4];
    u32 src = es & SENT;
    const u16* ap = (src == SENT) ? zp : (featb + (size_t)src * CI);
#pragma unroll
    for (int ks = 0; ks < 4; ++ks) a[ks] = *(const short8*)(ap + ks * 32 + lg * 8);
  };
  auto scat = [&](const uint4& sc, const f32x4& c0, const f32x4& c1) {
    u32 e[4] = {sc.x, sc.y, sc.z, sc.w};
#pragma unroll
    for (int r = 0; r < 4; ++r) {
      if (e[r] != SENT) {  // skip padding (r6 fix); wave owns its cols -> race-free
        int i0 = (int)(e[r] >> 18) * ACC_STRIDE + colbase;
        accb[i0] = f2bf(bf2f(accb[i0]) + c0[r]);
        accb[i0 + 16] = f2bf(bf2f(accb[i0 + 16]) + c1[r]);
      }
    }
  };

  // ---- k-major tile loop: B loaded ONCE per k, reused across its tiles ----
  for (int k = 0; k < KK; ++k) {
    const int cnt = cnt_lds[k];      // block-uniform
    if (cnt == 0) continue;
    const int ntk = (cnt + 15) >> 4;
    const int kb = kbase_of(k);
    short8 b[8];
    {
      const u16* wb = Wt3 + (size_t)(k * 32 + wv * 8) * 512 + lane * 8;
#pragma unroll
      for (int j = 0; j < 8; ++j) b[j] = *(const short8*)(wb + j * 512);
    }
    int t = 0;
    for (; t + 1 < ntk; t += 2) {   // paired: both gather sets in flight,
      uint4 sc0, sc1;               // MFMAs interleaved to force liveness
      short8 a0[4], a1[4];
      loadTile(kb + t * 16, sc0, a0);
      loadTile(kb + t * 16 + 16, sc1, a1);
      f32x4 p0a = {0.f, 0.f, 0.f, 0.f}, p0b = {0.f, 0.f, 0.f, 0.f};
      f32x4 p1a = {0.f, 0.f, 0.f, 0.f}, p1b = {0.f, 0.f, 0.f, 0.f};
#pragma unroll
      for (int ks = 0; ks < 4; ++ks) {
        p0a = __builtin_amdgcn_mfma_f32_16x16x32_bf16(a0[ks], b[ks], p0a, 0, 0, 0);
        p1a = __builtin_amdgcn_mfma_f32_16x16x32_bf16(a1[ks], b[ks], p1a, 0, 0, 0);
        p0b = __builtin_amdgcn_mfma_f32_16x16x32_bf16(a0[ks], b[4 + ks], p0b, 0, 0, 0);
        p1b = __builtin_amdgcn_mfma_f32_16x16x32_bf16(a1[ks], b[4 + ks], p1b, 0, 0, 0);
      }
      scat(sc0, p0a, p0b);
      scat(sc1, p1a, p1b);
    }
    if (t < ntk) {                  // odd tail
      uint4 sc0;
      short8 a0[4];
      loadTile(kb + t * 16, sc0, a0);
      f32x4 p0a = {0.f, 0.f, 0.f, 0.f}, p0b = {0.f, 0.f, 0.f, 0.f};
#pragma unroll
      for (int ks = 0; ks < 4; ++ks) {
        p0a = __builtin_amdgcn_mfma_f32_16x16x32_bf16(a0[ks], b[ks], p0a, 0, 0, 0);
        p0b = __builtin_amdgcn_mfma_f32_16x16x32_bf16(a0[ks], b[4 + ks], p0b, 0, 0, 0);
      }
      scat(sc0, p0a, p0b);
    }
  }
  __syncthreads();

  // epilogue: drain bf16 acc -> f32 out, accumulate BN partials
  float s4[4] = {0.f, 0.f, 0.f, 0.f}, q4[4] = {0.f, 0.f, 0.f, 0.f};
  const int col4 = (tid & 31) * 4;
  const int rgrp = tid >> 5;  // 0..7
#pragma unroll
  for (int i = 0; i < 24; ++i) {
    int row = rgrp + i * 8;
    const u16* ap = &accb[row * ACC_STRIDE + col4];
    float4 v;
    v.x = bf2f(ap[0]); v.y = bf2f(ap[1]); v.z = bf2f(ap[2]); v.w = bf2f(ap[3]);
    int grow = row0 + row;
    if (grow < N_VOX) {
      *(float4*)&out[(size_t)grow * CO + col4] = v;
      s4[0] += v.x; q4[0] += v.x * v.x;
      s4[1] += v.y; q4[1] += v.y * v.y;
      s4[2] += v.z; q4[2] += v.z * v.z;
      s4[3] += v.w; q4[3] += v.w * v.w;
    }
  }
  __syncthreads();  // acc reads done; ps alias safe
#pragma unroll
  for (int j = 0; j < 4; ++j) {
    ps[rgrp * 128 + col4 + j] = s4[j];
    ps[1024 + rgrp * 128 + col4 + j] = q4[j];
  }
  __syncthreads();
  {
    int col = tid & 127, which = tid >> 7;
    float acc = 0.f;
#pragma unroll
    for (int g = 0; g < 8; ++g) acc += ps[which * 1024 + g * 128 + col];
    partial[(size_t)bid * 256 + tid] = acc;
  }
}

// ---- fallback conv (fp32 gather via VGPR + writeA; B in regs from Wt3) ----
__global__ __launch_bounds__(256, 2) void conv_fb_kernel(
    const float* __restrict__ feat, const u16* __restrict__ Wt3,
    const int* __restrict__ nb, float* __restrict__ out,
    float* __restrict__ partial) {
  __shared__ __align__(16) char smem[46592];
  u16* const Ab = (u16*)smem;               // 2 x 16KB
  int* const nbs = (int*)(smem + 32768);    // 13824B
  float* const sq = (float*)smem;

  const int tid = threadIdx.x;
  const int bid = blockIdx.x;
  const int row0 = bid * 128;

  for (int i = tid; i < 128 * KK; i += 256) {
    int gi = row0 * KK + i;
    nbs[i] = (gi < N_VOX * KK) ? nb[gi] : -1;
  }
  __syncthreads();

  const int lane = tid & 63;
  const int wv = tid >> 6;
  const int wr = wv >> 1, wc = wv & 1;
  const int lr = lane & 15, lg = lane >> 4;
  const int arow = tid >> 1;
  const int acol = (tid & 1) * 32;

  f32x4 acc[4][4];
#pragma unroll
  for (int m = 0; m < 4; ++m)
#pragma unroll
    for (int n = 0; n < 4; ++n) acc[m][n] = (f32x4){0.f, 0.f, 0.f, 0.f};

  float4 af[8];
  short8 b0[8], b1[8];

  auto issueAf = [&](int s) {
    int k = s >> 1, half = (s & 1) * 64;
    int src = nbs[arow * KK + k];
    if (src >= 0) {
      const float4* p = (const float4*)(feat + (size_t)src * CI + half + acol);
#pragma unroll
      for (int j = 0; j < 8; ++j) af[j] = p[j];
    } else {
#pragma unroll
      for (int j = 0; j < 8; ++j) af[j] = (float4){0.f, 0.f, 0.f, 0.f};
    }
  };
  auto loadB = [&](int s, short8* bn) {
    int k = s >> 1, half = s & 1;
#pragma unroll
    for (int n = 0; n < 4; ++n)
#pragma unroll
      for (int ks = 0; ks < 2; ++ks)
        bn[n * 2 + ks] = *(const short8*)(Wt3 +
            (size_t)((k * 32 + (wc * 4 + n) * 4) + half * 2 + ks) * 512 + lane * 8);
  };
  auto writeA = [&](u16* Adst) {
    int v = arow & 7;
#pragma unroll
    for (int q = 0; q < 4; ++q) {
      u16 t8[8];
#pragma unroll
      for (int i = 0; i < 2; ++i) {
        float4 f = af[q * 2 + i];
        t8[i * 4 + 0] = cvt_bf(f.x); t8[i * 4 + 1] = cvt_bf(f.y);
        t8[i * 4 + 2] = cvt_bf(f.z); t8[i * 4 + 3] = cvt_bf(f.w);
      }
      int c_o = (tid & 1) * 4 + q;
      *(uint4*)&Adst[arow * 64 + ((c_o ^ v) << 3)] = *(const uint4*)t8;
    }
  };
  auto compute = [&](const u16* A, const short8* bc) {
#pragma unroll
    for (int ks = 0; ks < 2; ++ks) {
      short8 a[4];
#pragma unroll
      for (int m = 0; m < 4; ++m) {
        int r = wr * 64 + m * 16 + lr;
        a[m] = *(const short8*)((const char*)A + r * 128 +
                                ((ks * 64 + lg * 16) ^ ((r & 7) << 4)));
      }
#pragma unroll
      for (int m = 0; m < 4; ++m)
#pragma unroll
        for (int n = 0; n < 4; ++n)
          acc[m][n] = __builtin_amdgcn_mfma_f32_16x16x32_bf16(a[m], bc[n * 2 + ks],
                                                              acc[m][n], 0, 0, 0);
    }
  };

  issueAf(0);
  loadB(0, b0);
  for (int s = 0; s + 2 <= NSTEP - 1; s += 2) {
    writeA(Ab + (s & 1) * 8192); __syncthreads();
    issueAf(s + 1); loadB(s + 1, b1);
    compute(Ab + (s & 1) * 8192, b0);
    writeA(Ab + ((s + 1) & 1) * 8192); __syncthreads();
    issueAf(s + 2); loadB(s + 2, b0);
    compute(Ab + ((s + 1) & 1) * 8192, b1);
  }
  writeA(Ab); __syncthreads();
  issueAf(NSTEP - 1); loadB(NSTEP - 1, b1);
  compute(Ab, b0);
  writeA(Ab + 8192); __syncthreads();
  compute(Ab + 8192, b1);

  float sv[4], qv[4];
#pragma unroll
  for (int n = 0; n < 4; ++n) {
    float s = 0.f, q = 0.f;
    int col = wc * 64 + n * 16 + lr;
#pragma unroll
    for (int m = 0; m < 4; ++m) {
      int rb_ = row0 + wr * 64 + m * 16 + lg * 4;
#pragma unroll
      for (int e = 0; e < 4; ++e) {
        float x = acc[m][n][e];
        if (rb_ + e < N_VOX) out[(size_t)(rb_ + e) * CO + col] = x;
        s += x; q += x * x;
      }
    }
    s += __shfl_xor(s, 16, 64); s += __shfl_xor(s, 32, 64);
    q += __shfl_xor(q, 16, 64); q += __shfl_xor(q, 32, 64);
    sv[n] = s; qv[n] = q;
  }
  __syncthreads();
  if (lg == 0) {
#pragma unroll
    for (int n = 0; n < 4; ++n) {
      int col = wc * 64 + n * 16 + lr;
      sq[wr * 256 + col] = sv[n];
      sq[wr * 256 + 128 + col] = qv[n];
    }
  }
  __syncthreads();
  partial[(size_t)bid * 256 + tid] = sq[tid] + sq[256 + tid];
}

// ---- deterministic 2-stage channel reduction (param nblk) ----
__global__ __launch_bounds__(256) void reduce1_kernel(const float* __restrict__ partial,
                                                      float* __restrict__ partial2,
                                                      int nblk) {
  int t = threadIdx.x, b = blockIdx.x;
  float acc = 0.f;
  int jend = (b + 1) * 16; if (jend > nblk) jend = nblk;
  for (int j = b * 16; j < jend; ++j) acc += partial[(size_t)j * 256 + t];
  partial2[(size_t)b * 256 + t] = acc;
}

__global__ __launch_bounds__(256) void reduce2_kernel(const float* __restrict__ partial2,
                                                      const float* __restrict__ gamma,
                                                      const float* __restrict__ beta,
                                                      float* __restrict__ stats, int n2) {
  __shared__ float sums[256];
  int t = threadIdx.x;
  float acc = 0.f;
  for (int j = 0; j < n2; ++j) acc += partial2[(size_t)j * 256 + t];
  sums[t] = acc;
  __syncthreads();
  if (t < 128) {
    float mean = sums[t] / (float)N_VOX;
    float var = sums[128 + t] / (float)N_VOX - mean * mean;
    float scale = gamma[t] * rsqrtf(var + BN_EPS);
    stats[t] = scale;
    stats[128 + t] = beta[t] - mean * scale;
  }
}

// ---- BN apply + LeakyReLU, in place on d_out ----
__global__ __launch_bounds__(256) void bnact_kernel(float* __restrict__ out,
                                                    const float* __restrict__ stats) {
  __shared__ float s_scale[128], s_shift[128];
  int t = threadIdx.x;
  if (t < 128) { s_scale[t] = stats[t]; s_shift[t] = stats[128 + t]; }
  __syncthreads();
  size_t i = (size_t)blockIdx.x * 256 + t;
  float4* o4 = (float4*)out;
  float4 v = o4[i];
  int c0 = ((int)(i & 31)) << 2;
  float x;
  x = v.x * s_scale[c0 + 0] + s_shift[c0 + 0]; v.x = x > 0.f ? x : LEAK * x;
  x = v.y * s_scale[c0 + 1] + s_shift[c0 + 1]; v.y = x > 0.f ? x : LEAK * x;
  x = v.z * s_scale[c0 + 2] + s_shift[c0 + 2]; v.z = x > 0.f ? x : LEAK * x;
  x = v.w * s_scale[c0 + 3] + s_shift[c0 + 3]; v.w = x > 0.f ? x : LEAK * x;
  o4[i] = v;
}

extern "C" void kernel_launch(void* const* d_in, const int* in_sizes, int n_in,
                              void* d_out, int out_size, void* d_ws, size_t ws_size,
                              hipStream_t stream) {
  const float* feat  = (const float*)d_in[0];
  const float* W     = (const float*)d_in[1];
  // d_in[2] = bias: cancels exactly under training-mode batch norm -> skipped
  const float* gamma = (const float*)d_in[3];
  const float* beta  = (const float*)d_in[4];
  const int*   nb    = (const int*)d_in[5];
  float* out = (float*)d_out;

  char* ws = (char*)d_ws;
  u16*   Wt3      = (u16*)ws;                        // 884,736 B
  float* partial  = (float*)(ws + 884736);           // up to 1563*256*4 = 1,600,512 B
  float* partial2 = (float*)(ws + 2485248);          // 100,352 B
  float* stats    = (float*)(ws + 2585600);          // 1,024 B
  u16*   zp       = (u16*)(ws + 2586624);            // 256 B zeros
  u16*   featb    = (u16*)(ws + 2586880);            // 51,200,000 B
  const size_t need_fast = 53786880u;                // known OK (r7/r8/r12 ran fast path)

  hipLaunchKernelGGL(wcast3_kernel, dim3(216), dim3(256), 0, stream, W, Wt3);
  if (ws_size >= need_fast) {
    hipMemsetAsync(zp, 0, 256, stream);
    hipLaunchKernelGGL(fcast_kernel, dim3(12500), dim3(256), 0, stream, feat, featb);
    hipLaunchKernelGGL(conv_sp_kernel, dim3(NBLK192), dim3(256), 0, stream,
                       featb, Wt3, nb, zp, out, partial);
    hipLaunchKernelGGL(reduce1_kernel, dim3(66), dim3(256), 0, stream,
                       partial, partial2, NBLK192);
    hipLaunchKernelGGL(reduce2_kernel, dim3(1), dim3(256), 0, stream,
                       partial2, gamma, beta, stats, 66);
  } else {
    hipLaunchKernelGGL(conv_fb_kernel, dim3(NBLKFB), dim3(256), 0, stream,
                       feat, Wt3, nb, out, partial);
    hipLaunchKernelGGL(reduce1_kernel, dim3(98), dim3(256), 0, stream,
                       partial, partial2, NBLKFB);
    hipLaunchKernelGGL(reduce2_kernel, dim3(1), dim3(256), 0, stream,
                       partial2, gamma, beta, stats, 98);
  }
  hipLaunchKernelGGL(bnact_kernel, dim3(25000), dim3(256), 0, stream, out, stats);
}

// Round 14
// 300.688 us; speedup vs baseline: 1.0360x; 1.0360x over previous
//
#include <hip/hip_runtime.h>
#include <hip/hip_bf16.h>

#define N_VOX 200000
#define CI 128
#define CO 128
#define KK 27
#define BM 192
#define NBLK192 1042
#define NBLKFB 1563
#define NSTEP 54
#define LEAK 0.333f
#define BN_EPS 1e-4f
#define SENT 0x3FFFFu
#define ACC_STRIDE 132   // u16 units
#define RB_CAP 64

typedef unsigned short u16;
typedef unsigned int u32;
typedef __attribute__((ext_vector_type(8))) short short8;
typedef __attribute__((ext_vector_type(4))) float f32x4;

typedef const __attribute__((address_space(1))) u32* gptr_t;
typedef __attribute__((address_space(3))) u32* lptr_t;

__device__ __forceinline__ u16 f2bf(float f) {  // RNE
  union { float f; u32 u; } x; x.f = f;
  return (u16)((x.u + 0x7FFFu + ((x.u >> 16) & 1u)) >> 16);
}
__device__ __forceinline__ float bf2f(u16 h) {
  union { u32 u; float f; } x; x.u = ((u32)h) << 16;
  return x.f;
}
__device__ __forceinline__ u16 cvt_bf(float f) {
  union { __hip_bfloat16 h; u16 u; } c;
  c.h = __float2bfloat16(f);
  return c.u;
}
__device__ __forceinline__ int kbase_of(int k) {
  // center (k=13) has BM entries, others RB_CAP
  return (k < 13) ? k * RB_CAP : (k == 13 ? 13 * RB_CAP : 13 * RB_CAP + BM + (k - 14) * RB_CAP);
}

// ---- feature cast f32 -> bf16 ----
__global__ __launch_bounds__(256) void fcast_kernel(const float* __restrict__ f,
                                                    u16* __restrict__ fb) {
  size_t i = ((size_t)blockIdx.x * 256 + threadIdx.x) * 8;
  float4 a = *(const float4*)(f + i);
  float4 b = *(const float4*)(f + i + 4);
  u16 t[8];
  t[0] = cvt_bf(a.x); t[1] = cvt_bf(a.y); t[2] = cvt_bf(a.z); t[3] = cvt_bf(a.w);
  t[4] = cvt_bf(b.x); t[5] = cvt_bf(b.y); t[6] = cvt_bf(b.z); t[7] = cvt_bf(b.w);
  *(uint4*)(fb + i) = *(const uint4*)t;
}

// ---- W repack: chunk = k*32 + nf*4 + ks ; lane (lr,lg):
// Wt3[chunk*512 + lane*8 + e] = bf16(W[k][ks*32+lg*8+e][nf*16+lr]) ----
__global__ __launch_bounds__(256) void wcast3_kernel(const float* __restrict__ W,
                                                     u16* __restrict__ Wt3) {
  int gid = blockIdx.x * 256 + threadIdx.x;  // 55296 total
  int lane = gid & 63, chunk = gid >> 6;
  int ks = chunk & 3, nf = (chunk >> 2) & 7, k = chunk >> 5;
  int lr = lane & 15, lg = lane >> 4;
  int co = nf * 16 + lr;
  int ci0 = ks * 32 + lg * 8;
  const float* Wk = W + (size_t)k * CI * CO;
  u16 t[8];
#pragma unroll
  for (int e = 0; e < 8; ++e) t[e] = f2bf(Wk[(ci0 + e) * CO + co]);
  *(uint4*)(Wt3 + (size_t)gid * 8) = *(const uint4*)t;
}

// ---- sparse conv v9: BM=192 k-major, B dbuf prefetch across k, XCD swizzle,
//      bf16 LDS acc, barrier-free col-partitioned waves, paired tiles ----
__global__ __launch_bounds__(256, 2) void conv_sp_kernel(
    const u16* __restrict__ featb, const u16* __restrict__ Wt3,
    const int* __restrict__ nb, const u16* __restrict__ zp,
    float* __restrict__ out, float* __restrict__ partial) {
  __shared__ __align__(16) char smem[58240];
  u16* const accb = (u16*)smem;                  // 50688B [192][132] bf16
  u32* const rb_lds = (u32*)(smem + 50688);      // 7424B (1856 entries)
  int* const cnt_lds = (int*)(smem + 58112);     // 112B
  int* const wcnt = (int*)(smem + 58224);        // 16B
  float* const ps = (float*)smem;                // epilogue alias (8KB)

  const int tid = threadIdx.x;
  // XCD-aware bijective swizzle (m204): dispatch round-robins XCDs; give each
  // XCD a CONTIGUOUS data-block chunk so gather windows + Wt3 fit its 4MB L2.
  // 1042 = 8*130 + 2 -> xcd<2 own 131 blocks, else 130.
  const int orig = blockIdx.x;
  const int xcd = orig & 7, oidx = orig >> 3;
  const int bid = (xcd < 2) ? xcd * 131 + oidx : 262 + (xcd - 2) * 130 + oidx;
  const int row0 = bid * BM;
  const int lane = tid & 63;
  const int w = tid >> 6;

  // zero bf16 acc tile
  for (int i = tid; i < (BM * ACC_STRIDE) / 2; i += 256) ((u32*)accb)[i] = 0u;

  // ---- rulebook: per-k compacted (dst<<18|src), 16-padded with SENT ----
  {
    const bool inrow = (tid < BM) && (row0 + tid < N_VOX);
    const int* nbp = nb + (size_t)(row0 + tid) * KK;
    int vv[KK];
#pragma unroll
    for (int k = 0; k < KK; ++k) vv[k] = (k != 13 && inrow) ? nbp[k] : -1;
    if (tid < BM)
      rb_lds[13 * RB_CAP + tid] = ((u32)tid << 18) | (inrow ? (u32)(row0 + tid) : SENT);
    if (tid == 0) cnt_lds[13] = BM;
#pragma unroll
    for (int k = 0; k < KK; ++k) {
      if (k == 13) continue;
      bool valid = vv[k] >= 0;
      unsigned long long m = __ballot(valid);
      if (lane == 0) wcnt[w] = (int)__popcll(m);
      __syncthreads();
      int pos = (int)__popcll(m & ((1ull << lane) - 1ull));
      if (w >= 1) pos += wcnt[0];
      if (w >= 2) pos += wcnt[1];
      if (w >= 3) pos += wcnt[2];
      int cnt = wcnt[0] + wcnt[1] + wcnt[2] + wcnt[3];
      if (cnt > RB_CAP) cnt = RB_CAP;
      int kb = kbase_of(k);
      if (valid && pos < RB_CAP) rb_lds[kb + pos] = ((u32)tid << 18) | (u32)vv[k];
      int pe = (cnt + 15) & ~15;
      for (int i = cnt + tid; i < pe; i += 256) rb_lds[kb + i] = SENT;
      if (tid == 0) cnt_lds[k] = cnt;
      __syncthreads();
    }
  }

  const int wv = w;
  const int lr = lane & 15, lg = lane >> 4;
  const int colbase = wv * 32 + lr;

  auto loadTile = [&](int off, uint4& sc, short8* a) {
    u32 es = rb_lds[off + lr];
    sc = *(const uint4*)&rb_lds[off + lg * 4];
    u32 src = es & SENT;
    const u16* ap = (src == SENT) ? zp : (featb + (size_t)src * CI);
#pragma unroll
    for (int ks = 0; ks < 4; ++ks) a[ks] = *(const short8*)(ap + ks * 32 + lg * 8);
  };
  auto scat = [&](const uint4& sc, const f32x4& c0, const f32x4& c1) {
    u32 e[4] = {sc.x, sc.y, sc.z, sc.w};
#pragma unroll
    for (int r = 0; r < 4; ++r) {
      if (e[r] != SENT) {  // skip padding (r6 fix); wave owns its cols -> race-free
        int i0 = (int)(e[r] >> 18) * ACC_STRIDE + colbase;
        accb[i0] = f2bf(bf2f(accb[i0]) + c0[r]);
        accb[i0 + 16] = f2bf(bf2f(accb[i0 + 16]) + c1[r]);
      }
    }
  };
  auto loadB = [&](int k, short8* b) {   // clamped: harmless redundant load at tail
    if (k > KK - 1) k = KK - 1;
    const u16* wb = Wt3 + (size_t)(k * 32 + wv * 8) * 512 + lane * 8;
#pragma unroll
    for (int j = 0; j < 8; ++j) b[j] = *(const short8*)(wb + j * 512);
  };
  auto process = [&](int k, const short8* b) {
    if (k >= KK) return;
    const int cnt = cnt_lds[k];      // block-uniform
    const int ntk = (cnt + 15) >> 4;
    const int kb = kbase_of(k);
    int t = 0;
    for (; t + 1 < ntk; t += 2) {   // paired: both gather sets in flight,
      uint4 sc0, sc1;               // MFMAs interleaved to force liveness
      short8 a0[4], a1[4];
      loadTile(kb + t * 16, sc0, a0);
      loadTile(kb + t * 16 + 16, sc1, a1);
      f32x4 p0a = {0.f, 0.f, 0.f, 0.f}, p0b = {0.f, 0.f, 0.f, 0.f};
      f32x4 p1a = {0.f, 0.f, 0.f, 0.f}, p1b = {0.f, 0.f, 0.f, 0.f};
#pragma unroll
      for (int ks = 0; ks < 4; ++ks) {
        p0a = __builtin_amdgcn_mfma_f32_16x16x32_bf16(a0[ks], b[ks], p0a, 0, 0, 0);
        p1a = __builtin_amdgcn_mfma_f32_16x16x32_bf16(a1[ks], b[ks], p1a, 0, 0, 0);
        p0b = __builtin_amdgcn_mfma_f32_16x16x32_bf16(a0[ks], b[4 + ks], p0b, 0, 0, 0);
        p1b = __builtin_amdgcn_mfma_f32_16x16x32_bf16(a1[ks], b[4 + ks], p1b, 0, 0, 0);
      }
      scat(sc0, p0a, p0b);
      scat(sc1, p1a, p1b);
    }
    if (t < ntk) {                  // odd tail
      uint4 sc0;
      short8 a0[4];
      loadTile(kb + t * 16, sc0, a0);
      f32x4 p0a = {0.f, 0.f, 0.f, 0.f}, p0b = {0.f, 0.f, 0.f, 0.f};
#pragma unroll
      for (int ks = 0; ks < 4; ++ks) {
        p0a = __builtin_amdgcn_mfma_f32_16x16x32_bf16(a0[ks], b[ks], p0a, 0, 0, 0);
        p0b = __builtin_amdgcn_mfma_f32_16x16x32_bf16(a0[ks], b[4 + ks], p0b, 0, 0, 0);
      }
      scat(sc0, p0a, p0b);
    }
  };

  // ---- k-major loop, unrolled x2 for named B ping-pong (rule 20):
  //      B(k+1) prefetch issues BEFORE process(k) -> a full k of latency cover.
  {
    short8 b0[8], b1[8];
    loadB(0, b0);
    for (int k = 0; k < KK; k += 2) {
      loadB(k + 1, b1);
      process(k, b0);
      loadB(k + 2, b0);
      process(k + 1, b1);
    }
  }
  __syncthreads();

  // epilogue: drain bf16 acc -> f32 out, accumulate BN partials
  float s4[4] = {0.f, 0.f, 0.f, 0.f}, q4[4] = {0.f, 0.f, 0.f, 0.f};
  const int col4 = (tid & 31) * 4;
  const int rgrp = tid >> 5;  // 0..7
#pragma unroll
  for (int i = 0; i < 24; ++i) {
    int row = rgrp + i * 8;
    const u16* ap = &accb[row * ACC_STRIDE + col4];
    float4 v;
    v.x = bf2f(ap[0]); v.y = bf2f(ap[1]); v.z = bf2f(ap[2]); v.w = bf2f(ap[3]);
    int grow = row0 + row;
    if (grow < N_VOX) {
      *(float4*)&out[(size_t)grow * CO + col4] = v;
      s4[0] += v.x; q4[0] += v.x * v.x;
      s4[1] += v.y; q4[1] += v.y * v.y;
      s4[2] += v.z; q4[2] += v.z * v.z;
      s4[3] += v.w; q4[3] += v.w * v.w;
    }
  }
  __syncthreads();  // acc reads done; ps alias safe
#pragma unroll
  for (int j = 0; j < 4; ++j) {
    ps[rgrp * 128 + col4 + j] = s4[j];
    ps[1024 + rgrp * 128 + col4 + j] = q4[j];
  }
  __syncthreads();
  {
    int col = tid & 127, which = tid >> 7;
    float acc = 0.f;
#pragma unroll
    for (int g = 0; g < 8; ++g) acc += ps[which * 1024 + g * 128 + col];
    partial[(size_t)bid * 256 + tid] = acc;
  }
}

// ---- fallback conv (fp32 gather via VGPR + writeA; B in regs from Wt3) ----
__global__ __launch_bounds__(256, 2) void conv_fb_kernel(
    const float* __restrict__ feat, const u16* __restrict__ Wt3,
    const int* __restrict__ nb, float* __restrict__ out,
    float* __restrict__ partial) {
  __shared__ __align__(16) char smem[46592];
  u16* const Ab = (u16*)smem;               // 2 x 16KB
  int* const nbs = (int*)(smem + 32768);    // 13824B
  float* const sq = (float*)smem;

  const int tid = threadIdx.x;
  const int bid = blockIdx.x;
  const int row0 = bid * 128;

  for (int i = tid; i < 128 * KK; i += 256) {
    int gi = row0 * KK + i;
    nbs[i] = (gi < N_VOX * KK) ? nb[gi] : -1;
  }
  __syncthreads();

  const int lane = tid & 63;
  const int wv = tid >> 6;
  const int wr = wv >> 1, wc = wv & 1;
  const int lr = lane & 15, lg = lane >> 4;
  const int arow = tid >> 1;
  const int acol = (tid & 1) * 32;

  f32x4 acc[4][4];
#pragma unroll
  for (int m = 0; m < 4; ++m)
#pragma unroll
    for (int n = 0; n < 4; ++n) acc[m][n] = (f32x4){0.f, 0.f, 0.f, 0.f};

  float4 af[8];
  short8 b0[8], b1[8];

  auto issueAf = [&](int s) {
    int k = s >> 1, half = (s & 1) * 64;
    int src = nbs[arow * KK + k];
    if (src >= 0) {
      const float4* p = (const float4*)(feat + (size_t)src * CI + half + acol);
#pragma unroll
      for (int j = 0; j < 8; ++j) af[j] = p[j];
    } else {
#pragma unroll
      for (int j = 0; j < 8; ++j) af[j] = (float4){0.f, 0.f, 0.f, 0.f};
    }
  };
  auto loadB = [&](int s, short8* bn) {
    int k = s >> 1, half = s & 1;
#pragma unroll
    for (int n = 0; n < 4; ++n)
#pragma unroll
      for (int ks = 0; ks < 2; ++ks)
        bn[n * 2 + ks] = *(const short8*)(Wt3 +
            (size_t)((k * 32 + (wc * 4 + n) * 4) + half * 2 + ks) * 512 + lane * 8);
  };
  auto writeA = [&](u16* Adst) {
    int v = arow & 7;
#pragma unroll
    for (int q = 0; q < 4; ++q) {
      u16 t8[8];
#pragma unroll
      for (int i = 0; i < 2; ++i) {
        float4 f = af[q * 2 + i];
        t8[i * 4 + 0] = cvt_bf(f.x); t8[i * 4 + 1] = cvt_bf(f.y);
        t8[i * 4 + 2] = cvt_bf(f.z); t8[i * 4 + 3] = cvt_bf(f.w);
      }
      int c_o = (tid & 1) * 4 + q;
      *(uint4*)&Adst[arow * 64 + ((c_o ^ v) << 3)] = *(const uint4*)t8;
    }
  };
  auto compute = [&](const u16* A, const short8* bc) {
#pragma unroll
    for (int ks = 0; ks < 2; ++ks) {
      short8 a[4];
#pragma unroll
      for (int m = 0; m < 4; ++m) {
        int r = wr * 64 + m * 16 + lr;
        a[m] = *(const short8*)((const char*)A + r * 128 +
                                ((ks * 64 + lg * 16) ^ ((r & 7) << 4)));
      }
#pragma unroll
      for (int m = 0; m < 4; ++m)
#pragma unroll
        for (int n = 0; n < 4; ++n)
          acc[m][n] = __builtin_amdgcn_mfma_f32_16x16x32_bf16(a[m], bc[n * 2 + ks],
                                                              acc[m][n], 0, 0, 0);
    }
  };

  issueAf(0);
  loadB(0, b0);
  for (int s = 0; s + 2 <= NSTEP - 1; s += 2) {
    writeA(Ab + (s & 1) * 8192); __syncthreads();
    issueAf(s + 1); loadB(s + 1, b1);
    compute(Ab + (s & 1) * 8192, b0);
    writeA(Ab + ((s + 1) & 1) * 8192); __syncthreads();
    issueAf(s + 2); loadB(s + 2, b0);
    compute(Ab + ((s + 1) & 1) * 8192, b1);
  }
  writeA(Ab); __syncthreads();
  issueAf(NSTEP - 1); loadB(NSTEP - 1, b1);
  compute(Ab, b0);
  writeA(Ab + 8192); __syncthreads();
  compute(Ab + 8192, b1);

  float sv[4], qv[4];
#pragma unroll
  for (int n = 0; n < 4; ++n) {
    float s = 0.f, q = 0.f;
    int col = wc * 64 + n * 16 + lr;
#pragma unroll
    for (int m = 0; m < 4; ++m) {
      int rb_ = row0 + wr * 64 + m * 16 + lg * 4;
#pragma unroll
      for (int e = 0; e < 4; ++e) {
        float x = acc[m][n][e];
        if (rb_ + e < N_VOX) out[(size_t)(rb_ + e) * CO + col] = x;
        s += x; q += x * x;
      }
    }
    s += __shfl_xor(s, 16, 64); s += __shfl_xor(s, 32, 64);
    q += __shfl_xor(q, 16, 64); q += __shfl_xor(q, 32, 64);
    sv[n] = s; qv[n] = q;
  }
  __syncthreads();
  if (lg == 0) {
#pragma unroll
    for (int n = 0; n < 4; ++n) {
      int col = wc * 64 + n * 16 + lr;
      sq[wr * 256 + col] = sv[n];
      sq[wr * 256 + 128 + col] = qv[n];
    }
  }
  __syncthreads();
  partial[(size_t)bid * 256 + tid] = sq[tid] + sq[256 + tid];
}

// ---- deterministic 2-stage channel reduction (param nblk) ----
__global__ __launch_bounds__(256) void reduce1_kernel(const float* __restrict__ partial,
                                                      float* __restrict__ partial2,
                                                      int nblk) {
  int t = threadIdx.x, b = blockIdx.x;
  float acc = 0.f;
  int jend = (b + 1) * 16; if (jend > nblk) jend = nblk;
  for (int j = b * 16; j < jend; ++j) acc += partial[(size_t)j * 256 + t];
  partial2[(size_t)b * 256 + t] = acc;
}

__global__ __launch_bounds__(256) void reduce2_kernel(const float* __restrict__ partial2,
                                                      const float* __restrict__ gamma,
                                                      const float* __restrict__ beta,
                                                      float* __restrict__ stats, int n2) {
  __shared__ float sums[256];
  int t = threadIdx.x;
  float acc = 0.f;
  for (int j = 0; j < n2; ++j) acc += partial2[(size_t)j * 256 + t];
  sums[t] = acc;
  __syncthreads();
  if (t < 128) {
    float mean = sums[t] / (float)N_VOX;
    float var = sums[128 + t] / (float)N_VOX - mean * mean;
    float scale = gamma[t] * rsqrtf(var + BN_EPS);
    stats[t] = scale;
    stats[128 + t] = beta[t] - mean * scale;
  }
}

// ---- BN apply + LeakyReLU, in place on d_out ----
__global__ __launch_bounds__(256) void bnact_kernel(float* __restrict__ out,
                                                    const float* __restrict__ stats) {
  __shared__ float s_scale[128], s_shift[128];
  int t = threadIdx.x;
  if (t < 128) { s_scale[t] = stats[t]; s_shift[t] = stats[128 + t]; }
  __syncthreads();
  size_t i = (size_t)blockIdx.x * 256 + t;
  float4* o4 = (float4*)out;
  float4 v = o4[i];
  int c0 = ((int)(i & 31)) << 2;
  float x;
  x = v.x * s_scale[c0 + 0] + s_shift[c0 + 0]; v.x = x > 0.f ? x : LEAK * x;
  x = v.y * s_scale[c0 + 1] + s_shift[c0 + 1]; v.y = x > 0.f ? x : LEAK * x;
  x = v.z * s_scale[c0 + 2] + s_shift[c0 + 2]; v.z = x > 0.f ? x : LEAK * x;
  x = v.w * s_scale[c0 + 3] + s_shift[c0 + 3]; v.w = x > 0.f ? x : LEAK * x;
  o4[i] = v;
}

extern "C" void kernel_launch(void* const* d_in, const int* in_sizes, int n_in,
                              void* d_out, int out_size, void* d_ws, size_t ws_size,
                              hipStream_t stream) {
  const float* feat  = (const float*)d_in[0];
  const float* W     = (const float*)d_in[1];
  // d_in[2] = bias: cancels exactly under training-mode batch norm -> skipped
  const float* gamma = (const float*)d_in[3];
  const float* beta  = (const float*)d_in[4];
  const int*   nb    = (const int*)d_in[5];
  float* out = (float*)d_out;

  char* ws = (char*)d_ws;
  u16*   Wt3      = (u16*)ws;                        // 884,736 B
  float* partial  = (float*)(ws + 884736);           // up to 1563*256*4 = 1,600,512 B
  float* partial2 = (float*)(ws + 2485248);          // 100,352 B
  float* stats    = (float*)(ws + 2585600);          // 1,024 B
  u16*   zp       = (u16*)(ws + 2586624);            // 256 B zeros
  u16*   featb    = (u16*)(ws + 2586880);            // 51,200,000 B
  const size_t need_fast = 53786880u;                // known OK (r7/r8/r12 ran fast path)

  hipLaunchKernelGGL(wcast3_kernel, dim3(216), dim3(256), 0, stream, W, Wt3);
  if (ws_size >= need_fast) {
    hipMemsetAsync(zp, 0, 256, stream);
    hipLaunchKernelGGL(fcast_kernel, dim3(12500), dim3(256), 0, stream, feat, featb);
    hipLaunchKernelGGL(conv_sp_kernel, dim3(NBLK192), dim3(256), 0, stream,
                       featb, Wt3, nb, zp, out, partial);
    hipLaunchKernelGGL(reduce1_kernel, dim3(66), dim3(256), 0, stream,
                       partial, partial2, NBLK192);
    hipLaunchKernelGGL(reduce2_kernel, dim3(1), dim3(256), 0, stream,
                       partial2, gamma, beta, stats, 66);
  } else {
    hipLaunchKernelGGL(conv_fb_kernel, dim3(NBLKFB), dim3(256), 0, stream,
                       feat, Wt3, nb, out, partial);
    hipLaunchKernelGGL(reduce1_kernel, dim3(98), dim3(256), 0, stream,
                       partial, partial2, NBLKFB);
    hipLaunchKernelGGL(reduce2_kernel, dim3(1), dim3(256), 0, stream,
                       partial2, gamma, beta, stats, 98);
  }
  hipLaunchKernelGGL(bnact_kernel, dim3(25000), dim3(256), 0, stream, out, stats);
}